// Round 3
// baseline (1000.867 us; speedup 1.0000x reference)
//
#include <hip/hip_runtime.h>

// MoE FFN: D=1024, H=4096, E=8, top-2, T=4096 tokens, fp32 in/out, bf16 MFMA compute.
// R3: 256x256 tiles (halves re-read traffic; R2 showed fetch-volume-bound at ~2TB/s),
// merged shared+expert dispatches (z-plane roles), atomicAdd epilogue onto zeroed out.

#define T_TOKENS 4096
#define DM 1024
#define HID 4096
#define NE 8

typedef __attribute__((ext_vector_type(8))) short short8;
typedef __attribute__((ext_vector_type(4))) float f32x4;
typedef unsigned short u16;

__device__ __forceinline__ u16 f2b(float f) {
    unsigned u = __builtin_bit_cast(unsigned, f);
    u += 0x7FFFu + ((u >> 16) & 1u);   // round-to-nearest-even
    return (u16)(u >> 16);
}

__device__ __forceinline__ uint4 load8(const u16* p) { return *(const uint4*)p; }
__device__ __forceinline__ uint4 load8(const float* p) {
    const float4* q = (const float4*)p;
    float4 a = q[0], b = q[1];
    uint4 r;
    r.x = (unsigned)f2b(a.x) | ((unsigned)f2b(a.y) << 16);
    r.y = (unsigned)f2b(a.z) | ((unsigned)f2b(a.w) << 16);
    r.z = (unsigned)f2b(b.x) | ((unsigned)f2b(b.y) << 16);
    r.w = (unsigned)f2b(b.z) | ((unsigned)f2b(b.w) << 16);
    return r;
}

// async 16B global -> LDS (wave-uniform lds base + lane*16)
__device__ __forceinline__ void gld16(const u16* g, u16* lds) {
    __builtin_amdgcn_global_load_lds(
        (const __attribute__((address_space(1))) void*)g,
        (__attribute__((address_space(3))) void*)lds, 16, 0, 0);
}

// ---- fused fp32 -> bf16 conversion of all tensors --------------------------
constexpr long CN0 = (long)T_TOKENS * DM;        // x
constexpr long CN1 = CN0 + (long)HID * DM;       // sw1
constexpr long CN2 = CN1 + (long)DM * HID;       // sw2
constexpr long CN3 = CN2 + (long)NE * HID * DM;  // ew1
constexpr long CN4 = CN3 + (long)NE * DM * HID;  // ew2

__global__ __launch_bounds__(256) void cvt_all_kernel(
    const float* __restrict__ x,  const float* __restrict__ sw1,
    const float* __restrict__ sw2, const float* __restrict__ ew1,
    const float* __restrict__ ew2,
    u16* __restrict__ xb, u16* __restrict__ sw1b, u16* __restrict__ sw2b,
    u16* __restrict__ ew1b, u16* __restrict__ ew2b) {
    long i = ((long)blockIdx.x * 256 + threadIdx.x) * 8;
    const float* s; u16* d; long base;
    if (i < CN0)      { s = x;   d = xb;   base = 0;   }
    else if (i < CN1) { s = sw1; d = sw1b; base = CN0; }
    else if (i < CN2) { s = sw2; d = sw2b; base = CN1; }
    else if (i < CN3) { s = ew1; d = ew1b; base = CN2; }
    else if (i < CN4) { s = ew2; d = ew2b; base = CN3; }
    else return;
    long j = i - base;
    *(uint4*)(d + j) = load8(s + j);
}

// ---- gating (fp32: bf16 logits would flip near-tie expert picks) -----------
__global__ __launch_bounds__(256) void gate_kernel(const float* __restrict__ x,
                                                   const float* __restrict__ gw,
                                                   int* __restrict__ cnt,
                                                   int2* __restrict__ topidx,
                                                   float2* __restrict__ topg) {
    int t = blockIdx.x * 4 + (threadIdx.x >> 6);
    int lane = threadIdx.x & 63;
    const float* xr = x + (long)t * DM;
    float s[NE];
#pragma unroll
    for (int e = 0; e < NE; e++) s[e] = 0.f;
    for (int i = lane; i < DM; i += 64) {
        float xv = xr[i];
#pragma unroll
        for (int e = 0; e < NE; e++) s[e] += xv * gw[e * DM + i];
    }
#pragma unroll
    for (int e = 0; e < NE; e++)
        for (int o = 32; o > 0; o >>= 1) s[e] += __shfl_down(s[e], o);
    if (lane == 0) {
        int i0 = 0; float l0 = s[0];
#pragma unroll
        for (int e = 1; e < NE; e++) if (s[e] > l0) { l0 = s[e]; i0 = e; }
        int i1 = -1; float l1 = -1e30f;
#pragma unroll
        for (int e = 0; e < NE; e++) if (e != i0 && s[e] > l1) { l1 = s[e]; i1 = e; }
        float e1 = __expf(l1 - l0);
        float inv = 1.f / (1.f + e1);
        topidx[t] = make_int2(i0, i1);
        topg[t]   = make_float2(inv, e1 * inv);
        atomicAdd(&cnt[i0], 1);
        atomicAdd(&cnt[i1], 1);
    }
}

__global__ void prefix_kernel(const int* __restrict__ cnt, int* __restrict__ offs) {
    if (threadIdx.x == 0) {
        int a = 0;
        for (int e = 0; e < NE; e++) { offs[e] = a; a += cnt[e]; }
    }
}

__global__ __launch_bounds__(256) void scatter_kernel(const int2* __restrict__ topidx,
                                                      const float2* __restrict__ topg,
                                                      const int* __restrict__ offs,
                                                      int* __restrict__ fill,
                                                      int* __restrict__ tok,
                                                      float* __restrict__ gate) {
    int t = blockIdx.x * 256 + threadIdx.x;
    if (t >= T_TOKENS) return;
    int2 ix = topidx[t]; float2 g = topg[t];
    int p = atomicAdd(&fill[ix.x], 1);
    int sl = offs[ix.x] + p;
    tok[sl] = t; gate[sl] = g.x;
    p = atomicAdd(&fill[ix.y], 1);
    sl = offs[ix.y] + p;
    tok[sl] = t; gate[sl] = g.y;
}

// ---- merged MoE GEMM, 256x256 tile, 512 threads (8 waves of 64x128) --------
// PHASE 1: hid = silu(x * W1^T); z=0 shared -> hidS, z>=1 expert e=z-1 (gathered
//          token rows) -> hidE at slot rows.
// PHASE 2: out += gate * (hid * W2^T); z=0 shared (gate=1), z>=1 expert. All
//          atomicAdd onto zeroed out (roles run concurrently in one dispatch).
// A and B both K-contiguous with ld == K. Chunk swizzle (R2-verified, 0 bank
// conflicts): logical (row,kg) at physical chunk row*4 + (kg ^ ((row>>1)&3)).
template<int PHASE>
__global__ __launch_bounds__(512)
void gemm_moe(const u16* __restrict__ Ash, const u16* __restrict__ Aex,
              const u16* __restrict__ Bsh, const u16* __restrict__ Bex,
              const int* __restrict__ cnt, const int* __restrict__ offs,
              const int* __restrict__ tok_of_slot, const float* __restrict__ gate_of_slot,
              u16* __restrict__ hidS, u16* __restrict__ hidE,
              float* __restrict__ out) {
    constexpr int K  = (PHASE == 1) ? DM : HID;   // ld of A and B
    constexpr int NN = (PHASE == 1) ? HID : DM;

    const int z = blockIdx.z;
    int M, base;
    const u16 *A, *B;
    if (z == 0) { M = T_TOKENS; base = 0; A = Ash; B = Bsh; }
    else {
        int e = z - 1;
        base = offs[e]; M = cnt[e];
        A = Aex;
        B = Bex + (long)e * NN * K;
    }
    const int m0 = blockIdx.y * 256;
    if (m0 >= M) return;
    const int n0 = blockIdx.x * 256;

    __shared__ u16 As[256 * 32];   // unpadded: required by global_load_lds
    __shared__ u16 Bs[256 * 32];

    const int tid  = threadIdx.x;
    const int lane = tid & 63;
    const int wid  = tid >> 6;
    const int wm   = (wid >> 1) * 64;      // 4 row-panels of 64
    const int wn   = (wid & 1) * 128;      // 2 col-panels of 128
    const int lr   = lane & 15;

    // Staging: 1024 chunks (16 B) per matrix per K-slab; 2 rounds x 512 threads.
    const u16* aptr[2]; const u16* bptr[2];
    u16* alds[2]; u16* blds[2];
#pragma unroll
    for (int i = 0; i < 2; i++) {
        int p = tid + i * 512;
        int r = p >> 2;
        int kg = (p & 3) ^ ((r >> 1) & 3);
        int rr = m0 + r;
        if (rr >= M) rr = M - 1;           // clamp tail (stores guarded)
        long grow;
        if constexpr (PHASE == 1) grow = (z == 0) ? (long)rr : (long)tok_of_slot[base + rr];
        else                      grow = (z == 0) ? (long)rr : (long)(base + rr);
        aptr[i] = A + grow * (long)K + kg * 8;
        bptr[i] = B + (long)(n0 + r) * K + kg * 8;
        alds[i] = As + (i * 512 + wid * 64) * 8;   // wave-uniform base
        blds[i] = Bs + (i * 512 + wid * 64) * 8;
    }

    // Fragment read offsets; key invariant across mi/ni (row steps of 16/64).
    const int key = (lr >> 1) & 3;
    const int kgx = (lane >> 4) ^ key;
    const int aoe = (wm + lr) * 32 + kgx * 8;
    const int boe = (wn + lr) * 32 + kgx * 8;

    f32x4 acc[4][8];
#pragma unroll
    for (int mi = 0; mi < 4; mi++)
#pragma unroll
        for (int ni = 0; ni < 8; ni++)
            acc[mi][ni] = (f32x4){0.f, 0.f, 0.f, 0.f};

    for (int k0 = 0; k0 < K; k0 += 32) {
#pragma unroll
        for (int i = 0; i < 2; i++) {
            gld16(aptr[i] + k0, alds[i]);
            gld16(bptr[i] + k0, blds[i]);
        }
        __syncthreads();
        short8 af[4], bfr[8];
#pragma unroll
        for (int mi = 0; mi < 4; mi++) af[mi]  = *(const short8*)&As[aoe + mi * 512];
#pragma unroll
        for (int ni = 0; ni < 8; ni++) bfr[ni] = *(const short8*)&Bs[boe + ni * 512];
#pragma unroll
        for (int mi = 0; mi < 4; mi++)
#pragma unroll
            for (int ni = 0; ni < 8; ni++)
                acc[mi][ni] = __builtin_amdgcn_mfma_f32_16x16x32_bf16(af[mi], bfr[ni],
                                                                      acc[mi][ni], 0, 0, 0);
        __syncthreads();
    }

    // Epilogue. C/D layout: col = lane&15, row = (lane>>4)*4 + reg  [m89-verified]
    const int r4 = (lane >> 4) * 4;
    const int cl = lane & 15;
#pragma unroll
    for (int mi = 0; mi < 4; mi++) {
#pragma unroll
        for (int rr = 0; rr < 4; rr++) {
            int row = m0 + wm + mi * 16 + r4 + rr;
            if (row >= M) continue;
            long drow; float g = 1.f; long trow = row;
            if constexpr (PHASE == 1) {
                drow = (z == 0) ? (long)row : (long)(base + row);
            } else {
                if (z != 0) {
                    trow = tok_of_slot[base + row];
                    g    = gate_of_slot[base + row];
                }
            }
#pragma unroll
            for (int ni = 0; ni < 8; ni++) {
                int col = n0 + wn + ni * 16 + cl;
                float v = acc[mi][ni][rr];
                if constexpr (PHASE == 1) {
                    float s = v / (1.f + __expf(-v));
                    ((z == 0) ? hidS : hidE)[drow * HID + col] = f2b(s);
                } else {
                    atomicAdd(&out[trow * DM + col], g * v);
                }
            }
        }
    }
}

extern "C" void kernel_launch(void* const* d_in, const int* in_sizes, int n_in,
                              void* d_out, int out_size, void* d_ws, size_t ws_size,
                              hipStream_t stream) {
    const float* x   = (const float*)d_in[0];
    const float* sw1 = (const float*)d_in[1];
    const float* sw2 = (const float*)d_in[2];
    const float* ew1 = (const float*)d_in[3];
    const float* ew2 = (const float*)d_in[4];
    const float* gw  = (const float*)d_in[5];
    float* out = (float*)d_out;

    char* ws = (char*)d_ws;
    size_t off = 0;
    auto alloc = [&](size_t bytes) -> char* {
        off = (off + 255) & ~(size_t)255;
        char* p = ws + off;
        off += bytes;
        return p;
    };

    int*    meta   = (int*)alloc(256);          // cnt[8] | fill[8] | offs[8]
    int*    cnt    = meta;
    int*    fill   = meta + 8;
    int*    offs   = meta + 16;
    int2*   topidx = (int2*)alloc((size_t)T_TOKENS * 8);
    float2* topg   = (float2*)alloc((size_t)T_TOKENS * 8);
    int*    tok    = (int*)alloc((size_t)2 * T_TOKENS * 4);
    float*  gate   = (float*)alloc((size_t)2 * T_TOKENS * 4);
    u16* xb   = (u16*)alloc((size_t)T_TOKENS * DM * 2);
    u16* sw1b = (u16*)alloc((size_t)HID * DM * 2);
    u16* sw2b = (u16*)alloc((size_t)DM * HID * 2);
    u16* hidS = (u16*)alloc((size_t)T_TOKENS * HID * 2);
    u16* hidE = (u16*)alloc((size_t)2 * T_TOKENS * HID * 2);
    u16* ew1b = (u16*)alloc((size_t)NE * HID * DM * 2);
    u16* ew2b = (u16*)alloc((size_t)NE * DM * HID * 2);

    hipMemsetAsync(meta, 0, 64, stream);                       // cnt+fill
    hipMemsetAsync(out, 0, (size_t)T_TOKENS * DM * 4, stream); // atomicAdd target

    cvt_all_kernel<<<(int)(CN4 / 2048), 256, 0, stream>>>(
        x, sw1, sw2, ew1, ew2, xb, sw1b, sw2b, ew1b, ew2b);

    gate_kernel<<<T_TOKENS / 4, 256, 0, stream>>>(x, gw, cnt, topidx, topg);
    prefix_kernel<<<1, 64, 0, stream>>>(cnt, offs);
    scatter_kernel<<<T_TOKENS / 256, 256, 0, stream>>>(topidx, topg, offs, fill, tok, gate);

    // Phase 1: hidS / hidE = silu(x * W1^T)   grid: 16 n-tiles x 16 m-tiles x 9 roles
    gemm_moe<1><<<dim3(HID / 256, T_TOKENS / 256, NE + 1), 512, 0, stream>>>(
        xb, xb, sw1b, ew1b, cnt, offs, tok, gate, hidS, hidE, out);
    // Phase 2: out += gate * (hid * W2^T)     grid: 4 x 16 x 9
    gemm_moe<2><<<dim3(DM / 256, T_TOKENS / 256, NE + 1), 512, 0, stream>>>(
        hidS, hidE, sw2b, ew2b, cnt, offs, tok, gate, nullptr, nullptr, out);
}

// Round 4
// 957.544 us; speedup vs baseline: 1.0452x; 1.0452x over previous
//
#include <hip/hip_runtime.h>

// MoE FFN: D=1024, H=4096, E=8, top-2, T=4096 tokens, fp32 in/out, bf16 MFMA compute.
// R4: back to 128x128/256t tiles (R3's 256^2 hit 1-block/CU occupancy cliff -> latency
// exposed). Weight cvt pass eliminated: B read as fp32, converted in-register during
// LDS staging. Shared+expert planes merged per phase (z) for waves-in-flight.

#define T_TOKENS 4096
#define DM 1024
#define HID 4096
#define NE 8

typedef __attribute__((ext_vector_type(8))) short short8;
typedef __attribute__((ext_vector_type(4))) float f32x4;
typedef unsigned short u16;

__device__ __forceinline__ u16 f2b(float f) {
    unsigned u = __builtin_bit_cast(unsigned, f);
    u += 0x7FFFu + ((u >> 16) & 1u);   // round-to-nearest-even
    return (u16)(u >> 16);
}

__device__ __forceinline__ uint4 load8(const u16* p) { return *(const uint4*)p; }
__device__ __forceinline__ uint4 load8f(const float* p) {
    const float4* q = (const float4*)p;
    float4 a = q[0], b = q[1];
    uint4 r;
    r.x = (unsigned)f2b(a.x) | ((unsigned)f2b(a.y) << 16);
    r.y = (unsigned)f2b(a.z) | ((unsigned)f2b(a.w) << 16);
    r.z = (unsigned)f2b(b.x) | ((unsigned)f2b(b.y) << 16);
    r.w = (unsigned)f2b(b.z) | ((unsigned)f2b(b.w) << 16);
    return r;
}

// async 16B global -> LDS (wave-uniform lds base + lane*16)
__device__ __forceinline__ void gld16(const u16* g, u16* lds) {
    __builtin_amdgcn_global_load_lds(
        (const __attribute__((address_space(1))) void*)g,
        (__attribute__((address_space(3))) void*)lds, 16, 0, 0);
}

__global__ __launch_bounds__(256) void cvt_x_kernel(const float* __restrict__ x,
                                                    u16* __restrict__ xb) {
    long i = ((long)blockIdx.x * 256 + threadIdx.x) * 8;
    *(uint4*)(xb + i) = load8f(x + i);
}

// ---- gating (fp32: bf16 logits would flip near-tie expert picks) -----------
__global__ __launch_bounds__(256) void gate_kernel(const float* __restrict__ x,
                                                   const float* __restrict__ gw,
                                                   int* __restrict__ cnt,
                                                   int2* __restrict__ topidx,
                                                   float2* __restrict__ topg) {
    int t = blockIdx.x * 4 + (threadIdx.x >> 6);
    int lane = threadIdx.x & 63;
    const float* xr = x + (long)t * DM;
    float s[NE];
#pragma unroll
    for (int e = 0; e < NE; e++) s[e] = 0.f;
    for (int i = lane; i < DM; i += 64) {
        float xv = xr[i];
#pragma unroll
        for (int e = 0; e < NE; e++) s[e] += xv * gw[e * DM + i];
    }
#pragma unroll
    for (int e = 0; e < NE; e++)
        for (int o = 32; o > 0; o >>= 1) s[e] += __shfl_down(s[e], o);
    if (lane == 0) {
        int i0 = 0; float l0 = s[0];
#pragma unroll
        for (int e = 1; e < NE; e++) if (s[e] > l0) { l0 = s[e]; i0 = e; }
        int i1 = -1; float l1 = -1e30f;
#pragma unroll
        for (int e = 0; e < NE; e++) if (e != i0 && s[e] > l1) { l1 = s[e]; i1 = e; }
        float e1 = __expf(l1 - l0);
        float inv = 1.f / (1.f + e1);
        topidx[t] = make_int2(i0, i1);
        topg[t]   = make_float2(inv, e1 * inv);
        atomicAdd(&cnt[i0], 1);
        atomicAdd(&cnt[i1], 1);
    }
}

__global__ void prefix_kernel(const int* __restrict__ cnt, int* __restrict__ offs) {
    if (threadIdx.x == 0) {
        int a = 0;
        for (int e = 0; e < NE; e++) { offs[e] = a; a += cnt[e]; }
    }
}

__global__ __launch_bounds__(256) void scatter_kernel(const int2* __restrict__ topidx,
                                                      const float2* __restrict__ topg,
                                                      const int* __restrict__ offs,
                                                      int* __restrict__ fill,
                                                      int* __restrict__ tok,
                                                      float* __restrict__ gate) {
    int t = blockIdx.x * 256 + threadIdx.x;
    if (t >= T_TOKENS) return;
    int2 ix = topidx[t]; float2 g = topg[t];
    int p = atomicAdd(&fill[ix.x], 1);
    int sl = offs[ix.x] + p;
    tok[sl] = t; gate[sl] = g.x;
    p = atomicAdd(&fill[ix.y], 1);
    sl = offs[ix.y] + p;
    tok[sl] = t; gate[sl] = g.y;
}

// ---- merged MoE GEMM, 128x128 tile, 256 threads --------------------------
// A (tokens/hid) is bf16, staged async via global_load_lds. B (weights) is fp32,
// staged sync with in-register bf16 convert (kills the weight-cvt pass).
// z=0: shared role; z>=1: expert e=z-1.
// PHASE 1: hid = silu(A * W1^T) -> hidS (z=0) / hidE slot rows (z>=1).
// PHASE 2: out += gate * (hid * W2^T), atomicAdd onto zeroed out.
// LDS chunk swizzle (R2-verified, 0 conflicts): logical (row,kg) at physical
// chunk row*4 + (kg ^ ((row>>1)&3)).
template<int PHASE>
__global__ __launch_bounds__(256)
void gemm_moe(const u16* __restrict__ Ash, const u16* __restrict__ Aex,
              const float* __restrict__ Bsh, const float* __restrict__ Bex,
              const int* __restrict__ cnt, const int* __restrict__ offs,
              const int* __restrict__ tok_of_slot, const float* __restrict__ gate_of_slot,
              u16* __restrict__ hidS, u16* __restrict__ hidE,
              float* __restrict__ out) {
    constexpr int K  = (PHASE == 1) ? DM : HID;
    constexpr int NN = (PHASE == 1) ? HID : DM;

    const int z = blockIdx.z;
    int M, base;
    const u16* A;
    const float* B;
    if (z == 0) { M = T_TOKENS; base = 0; A = Ash; B = Bsh; }
    else {
        int e = z - 1;
        base = offs[e]; M = cnt[e];
        A = Aex;
        B = Bex + (long)e * ((long)NN * K);
    }
    const int m0 = blockIdx.y * 128;
    if (m0 >= M) return;
    const int n0 = blockIdx.x * 128;

    __shared__ u16 As[128 * 32];   // unpadded (global_load_lds requirement)
    __shared__ u16 Bs[128 * 32];

    const int tid  = threadIdx.x;
    const int lane = tid & 63;
    const int wid  = tid >> 6;
    const int wm   = (wid >> 1) * 64;
    const int wn   = (wid & 1) * 64;
    const int lr   = lane & 15;

    // Staging: chunk p = tid + i*256; logical row r=p>>2, kg=(p&3)^((r>>1)&3).
    const u16* aptr[2]; u16* alds[2];
    const float* bsrc[2]; u16* bdst[2];
#pragma unroll
    for (int i = 0; i < 2; i++) {
        int p = tid + i * 256;
        int r = p >> 2;
        int kg = (p & 3) ^ ((r >> 1) & 3);
        int rr = m0 + r;
        if (rr >= M) rr = M - 1;           // clamp tail (stores guarded)
        long grow;
        if constexpr (PHASE == 1) grow = (z == 0) ? (long)rr : (long)tok_of_slot[base + rr];
        else                      grow = (z == 0) ? (long)rr : (long)(base + rr);
        aptr[i] = A + grow * (long)K + kg * 8;
        alds[i] = As + (i * 256 + wid * 64) * 8;   // wave-uniform base; lane adds *16B
        bsrc[i] = B + (long)(n0 + r) * K + kg * 8;
        bdst[i] = Bs + p * 8;
    }

    // Fragment read offsets; xor key invariant across mi/ni (row steps of 16).
    const int key = (lr >> 1) & 3;
    const int kgx = (lane >> 4) ^ key;
    const int aoe = (wm + lr) * 32 + kgx * 8;
    const int boe = (wn + lr) * 32 + kgx * 8;

    f32x4 acc[4][4];
#pragma unroll
    for (int mi = 0; mi < 4; mi++)
#pragma unroll
        for (int ni = 0; ni < 4; ni++)
            acc[mi][ni] = (f32x4){0.f, 0.f, 0.f, 0.f};

    for (int k0 = 0; k0 < K; k0 += 32) {
#pragma unroll
        for (int i = 0; i < 2; i++) gld16(aptr[i] + k0, alds[i]);
        uint4 b0 = load8f(bsrc[0] + k0);
        uint4 b1 = load8f(bsrc[1] + k0);
        *(uint4*)bdst[0] = b0;
        *(uint4*)bdst[1] = b1;
        __syncthreads();
        short8 af[4], bfr[4];
#pragma unroll
        for (int mi = 0; mi < 4; mi++) af[mi]  = *(const short8*)&As[aoe + mi * 512];
#pragma unroll
        for (int ni = 0; ni < 4; ni++) bfr[ni] = *(const short8*)&Bs[boe + ni * 512];
#pragma unroll
        for (int mi = 0; mi < 4; mi++)
#pragma unroll
            for (int ni = 0; ni < 4; ni++)
                acc[mi][ni] = __builtin_amdgcn_mfma_f32_16x16x32_bf16(af[mi], bfr[ni],
                                                                      acc[mi][ni], 0, 0, 0);
        __syncthreads();
    }

    // Epilogue. C/D layout: col = lane&15, row = (lane>>4)*4 + reg  [m89-verified]
    const int r4 = (lane >> 4) * 4;
    const int cl = lane & 15;
#pragma unroll
    for (int mi = 0; mi < 4; mi++) {
#pragma unroll
        for (int rr = 0; rr < 4; rr++) {
            int row = m0 + wm + mi * 16 + r4 + rr;
            if (row >= M) continue;
            long trow = row; float g = 1.f;
            if constexpr (PHASE == 2) {
                if (z != 0) {
                    trow = tok_of_slot[base + row];
                    g    = gate_of_slot[base + row];
                }
            }
#pragma unroll
            for (int ni = 0; ni < 4; ni++) {
                int col = n0 + wn + ni * 16 + cl;
                float v = acc[mi][ni][rr];
                if constexpr (PHASE == 1) {
                    float s = v / (1.f + __expf(-v));
                    long drow = (z == 0) ? (long)row : (long)(base + row);
                    ((z == 0) ? hidS : hidE)[drow * HID + col] = f2b(s);
                } else {
                    atomicAdd(&out[trow * DM + col], g * v);
                }
            }
        }
    }
}

extern "C" void kernel_launch(void* const* d_in, const int* in_sizes, int n_in,
                              void* d_out, int out_size, void* d_ws, size_t ws_size,
                              hipStream_t stream) {
    const float* x   = (const float*)d_in[0];
    const float* sw1 = (const float*)d_in[1];
    const float* sw2 = (const float*)d_in[2];
    const float* ew1 = (const float*)d_in[3];
    const float* ew2 = (const float*)d_in[4];
    const float* gw  = (const float*)d_in[5];
    float* out = (float*)d_out;

    char* ws = (char*)d_ws;
    size_t off = 0;
    auto alloc = [&](size_t bytes) -> char* {
        off = (off + 255) & ~(size_t)255;
        char* p = ws + off;
        off += bytes;
        return p;
    };

    int*    meta   = (int*)alloc(256);          // cnt[8] | fill[8] | offs[8]
    int*    cnt    = meta;
    int*    fill   = meta + 8;
    int*    offs   = meta + 16;
    int2*   topidx = (int2*)alloc((size_t)T_TOKENS * 8);
    float2* topg   = (float2*)alloc((size_t)T_TOKENS * 8);
    int*    tok    = (int*)alloc((size_t)2 * T_TOKENS * 4);
    float*  gate   = (float*)alloc((size_t)2 * T_TOKENS * 4);
    u16* xb   = (u16*)alloc((size_t)T_TOKENS * DM * 2);
    u16* hidS = (u16*)alloc((size_t)T_TOKENS * HID * 2);
    u16* hidE = (u16*)alloc((size_t)2 * T_TOKENS * HID * 2);

    hipMemsetAsync(meta, 0, 64, stream);                       // cnt+fill
    hipMemsetAsync(out, 0, (size_t)T_TOKENS * DM * 4, stream); // atomicAdd target

    cvt_x_kernel<<<(T_TOKENS * DM) / 2048, 256, 0, stream>>>(x, xb);
    gate_kernel<<<T_TOKENS / 4, 256, 0, stream>>>(x, gw, cnt, topidx, topg);
    prefix_kernel<<<1, 64, 0, stream>>>(cnt, offs);
    scatter_kernel<<<T_TOKENS / 256, 256, 0, stream>>>(topidx, topg, offs, fill, tok, gate);

    // Phase 1: hid = silu(x * W1^T)   grid (32, 32, 9)
    gemm_moe<1><<<dim3(HID / 128, T_TOKENS / 128, NE + 1), 256, 0, stream>>>(
        xb, xb, sw1, ew1, cnt, offs, tok, gate, hidS, hidE, nullptr);
    // Phase 2: out += gate * (hid * W2^T)   grid (8, 32, 9)
    gemm_moe<2><<<dim3(DM / 128, T_TOKENS / 128, NE + 1), 256, 0, stream>>>(
        hidS, hidE, sw2, ew2, cnt, offs, tok, gate, nullptr, nullptr, out);
}